// Round 2
// baseline (690.852 us; speedup 1.0000x reference)
//
#include <hip/hip_runtime.h>

#define LVLS  16
#define TSZ   524288u          // 2^19
#define TMASK (TSZ - 1u)
#define PRIME 2654435761u
#define WIDTH 64
#define FIN   32               // L*F
#define NPTS  1048576

// floor(16 * g^l), g = 128^(1/15) — matches np float64 floor then f32 cast
__constant__ float RES[LVLS] = {16.f, 22.f, 30.f, 42.f, 58.f, 80.f, 111.f, 153.f,
                                212.f, 294.f, 406.f, 561.f, 776.f, 1072.f, 1482.f, 2048.f};

static __device__ __forceinline__ unsigned pack_bf16(float a, float b) {
    unsigned ua = __float_as_uint(a), ub = __float_as_uint(b);
    ua += 0x7FFFu + ((ua >> 16) & 1u);      // RNE (values finite, non-NaN)
    ub += 0x7FFFu + ((ub >> 16) & 1u);
    return (ua >> 16) | (ub & 0xFFFF0000u);
}

// ---------------- encode: 4 waves/block, wave w owns levels 4w..4w+3 of 64 points ----------------
__global__ __launch_bounds__(256) void ngp_encode(
    const float* __restrict__ x,
    const float* __restrict__ tables,
    unsigned* __restrict__ feat,   // [LVLS][N] packed bf16x2
    int N)
{
    const int lane = threadIdx.x & 63;
    const int wv   = threadIdx.x >> 6;            // 0..3 (wave-uniform)
    const int n    = blockIdx.x * 64 + lane;
    if (n >= N) return;

    const float2 xy = ((const float2*)x)[n];

    // compute all 16 gather addresses first, then issue all loads (max MLP)
    unsigned idx[16];
    float ux[4], uy[4];
    #pragma unroll
    for (int j = 0; j < 4; ++j) {
        const int l = wv * 4 + j;
        const float r = RES[l];
        const float sx = xy.x * r, sy = xy.y * r;
        const float fx = floorf(sx), fy = floorf(sy);
        ux[j] = sx - fx; uy[j] = sy - fy;
        const unsigned ix = (unsigned)(int)fx;
        const unsigned iy = (unsigned)(int)fy;
        const unsigned hy0 = iy * PRIME;
        const unsigned hy1 = (iy + 1u) * PRIME;
        idx[4*j + 0] = (ix ^ hy0) & TMASK;
        idx[4*j + 1] = ((ix + 1u) ^ hy0) & TMASK;
        idx[4*j + 2] = (ix ^ hy1) & TMASK;
        idx[4*j + 3] = ((ix + 1u) ^ hy1) & TMASK;
    }

    float2 f[16];
    #pragma unroll
    for (int j = 0; j < 4; ++j) {
        const int l = wv * 4 + j;
        const float2* tb = (const float2*)(tables + (size_t)l * (TSZ * 2));
        f[4*j + 0] = tb[idx[4*j + 0]];
        f[4*j + 1] = tb[idx[4*j + 1]];
        f[4*j + 2] = tb[idx[4*j + 2]];
        f[4*j + 3] = tb[idx[4*j + 3]];
    }

    #pragma unroll
    for (int j = 0; j < 4; ++j) {
        const int l = wv * 4 + j;
        const float w00 = (1.f - ux[j]) * (1.f - uy[j]);
        const float w10 = ux[j] * (1.f - uy[j]);
        const float w01 = (1.f - ux[j]) * uy[j];
        const float w11 = ux[j] * uy[j];
        const float e0 = w00*f[4*j+0].x + w10*f[4*j+1].x + w01*f[4*j+2].x + w11*f[4*j+3].x;
        const float e1 = w00*f[4*j+0].y + w10*f[4*j+1].y + w01*f[4*j+2].y + w11*f[4*j+3].y;
        feat[(size_t)l * N + n] = pack_bf16(e0, e1);   // lanes = consecutive n -> coalesced
    }
}

// ---------------- MLP: thread per point, weights in LDS ----------------
__global__ __launch_bounds__(256) void ngp_mlp(
    const unsigned* __restrict__ feat,
    const float* __restrict__ W0, const float* __restrict__ b0,
    const float* __restrict__ W1, const float* __restrict__ b1,
    const float* __restrict__ W2, const float* __restrict__ b2,
    float* __restrict__ out, int N)
{
    __shared__ float sW0[FIN * WIDTH];
    __shared__ float sW1[WIDTH * WIDTH];
    __shared__ float sW2[WIDTH * 4];
    __shared__ float sB0[WIDTH];
    __shared__ float sB1[WIDTH];
    __shared__ float sB2[4];

    const int tid = threadIdx.x;
    for (int i = tid; i < FIN * WIDTH; i += 256) sW0[i] = W0[i];
    for (int i = tid; i < WIDTH * WIDTH; i += 256) sW1[i] = W1[i];
    if (tid < WIDTH) {
        sB0[tid] = b0[tid];
        sB1[tid] = b1[tid];
        sW2[tid * 4 + 0] = W2[tid * 3 + 0];
        sW2[tid * 4 + 1] = W2[tid * 3 + 1];
        sW2[tid * 4 + 2] = W2[tid * 3 + 2];
        sW2[tid * 4 + 3] = 0.f;
    }
    if (tid < 4) sB2[tid] = (tid < 3) ? b2[tid] : 0.f;
    __syncthreads();

    const int n = blockIdx.x * 256 + tid;
    if (n >= N) return;

    // gather the 16 packed feature words (all independent, coalesced)
    unsigned fw[LVLS];
    #pragma unroll
    for (int l = 0; l < LVLS; ++l) fw[l] = feat[(size_t)l * N + n];

    float h0[FIN];
    #pragma unroll
    for (int l = 0; l < LVLS; ++l) {
        h0[2*l]     = __uint_as_float(fw[l] << 16);
        h0[2*l + 1] = __uint_as_float(fw[l] & 0xFFFF0000u);
    }

    // ---- layer 0: 32 -> 64, ReLU ----
    float4 acc[16];
    #pragma unroll
    for (int j = 0; j < 16; ++j) acc[j] = ((const float4*)sB0)[j];
    #pragma unroll
    for (int i = 0; i < FIN; ++i) {
        const float v = h0[i];
        const float4* w = (const float4*)(sW0 + i * WIDTH);
        #pragma unroll
        for (int j = 0; j < 16; ++j) {
            const float4 ww = w[j];
            acc[j].x = fmaf(v, ww.x, acc[j].x);
            acc[j].y = fmaf(v, ww.y, acc[j].y);
            acc[j].z = fmaf(v, ww.z, acc[j].z);
            acc[j].w = fmaf(v, ww.w, acc[j].w);
        }
    }
    float h1[WIDTH];
    #pragma unroll
    for (int j = 0; j < 16; ++j) {
        h1[4*j + 0] = fmaxf(acc[j].x, 0.f);
        h1[4*j + 1] = fmaxf(acc[j].y, 0.f);
        h1[4*j + 2] = fmaxf(acc[j].z, 0.f);
        h1[4*j + 3] = fmaxf(acc[j].w, 0.f);
    }

    // ---- layer 1: 64 -> 64, ReLU ----
    #pragma unroll
    for (int j = 0; j < 16; ++j) acc[j] = ((const float4*)sB1)[j];
    #pragma unroll
    for (int i = 0; i < WIDTH; ++i) {
        const float v = h1[i];
        const float4* w = (const float4*)(sW1 + i * WIDTH);
        #pragma unroll
        for (int j = 0; j < 16; ++j) {
            const float4 ww = w[j];
            acc[j].x = fmaf(v, ww.x, acc[j].x);
            acc[j].y = fmaf(v, ww.y, acc[j].y);
            acc[j].z = fmaf(v, ww.z, acc[j].z);
            acc[j].w = fmaf(v, ww.w, acc[j].w);
        }
    }
    float h2[WIDTH];
    #pragma unroll
    for (int j = 0; j < 16; ++j) {
        h2[4*j + 0] = fmaxf(acc[j].x, 0.f);
        h2[4*j + 1] = fmaxf(acc[j].y, 0.f);
        h2[4*j + 2] = fmaxf(acc[j].z, 0.f);
        h2[4*j + 3] = fmaxf(acc[j].w, 0.f);
    }

    // ---- layer 2: 64 -> 3, sigmoid ----
    float o0 = sB2[0], o1 = sB2[1], o2 = sB2[2];
    #pragma unroll
    for (int i = 0; i < WIDTH; ++i) {
        const float4 w = ((const float4*)sW2)[i];
        const float v = h2[i];
        o0 = fmaf(v, w.x, o0);
        o1 = fmaf(v, w.y, o1);
        o2 = fmaf(v, w.z, o2);
    }
    o0 = 1.f / (1.f + __expf(-o0));
    o1 = 1.f / (1.f + __expf(-o1));
    o2 = 1.f / (1.f + __expf(-o2));

    out[(size_t)n * 3 + 0] = o0;
    out[(size_t)n * 3 + 1] = o1;
    out[(size_t)n * 3 + 2] = o2;
}

extern "C" void kernel_launch(void* const* d_in, const int* in_sizes, int n_in,
                              void* d_out, int out_size, void* d_ws, size_t ws_size,
                              hipStream_t stream) {
    const float* x      = (const float*)d_in[0];
    const float* tables = (const float*)d_in[1];
    const float* W0     = (const float*)d_in[2];
    const float* b0     = (const float*)d_in[3];
    const float* W1     = (const float*)d_in[4];
    const float* b1     = (const float*)d_in[5];
    const float* W2     = (const float*)d_in[6];
    const float* b2     = (const float*)d_in[7];
    float* out = (float*)d_out;
    unsigned* feat = (unsigned*)d_ws;          // LVLS * N * 4 B = 64 MB

    const int N = in_sizes[0] / 2;
    ngp_encode<<<(N + 63) / 64, 256, 0, stream>>>(x, tables, feat, N);
    ngp_mlp<<<(N + 255) / 256, 256, 0, stream>>>(feat, W0, b0, W1, b1, W2, b2, out, N);
}

// Round 3
// 308.227 us; speedup vs baseline: 2.2414x; 2.2414x over previous
//
#include <hip/hip_runtime.h>

#define LVLS  16
#define TSZ   524288u          // 2^19
#define TMASK (TSZ - 1u)
#define PRIME 2654435761u

// floor(16 * g^l), g = 128^(1/15) — matches np float64 floor then f32 cast
__constant__ float RES[LVLS] = {16.f, 22.f, 30.f, 42.f, 58.f, 80.f, 111.f, 153.f,
                                212.f, 294.f, 406.f, 561.f, 776.f, 1072.f, 1482.f, 2048.f};

typedef __bf16 bf16x8 __attribute__((ext_vector_type(8)));
typedef float  f32x4  __attribute__((ext_vector_type(4)));

union Frag {
    uint4          q;
    unsigned       u[4];
    unsigned short s[8];
    bf16x8         v;
};

static __device__ __forceinline__ unsigned short f2bf(float f) {
    unsigned u = __float_as_uint(f);
    u += 0x7FFFu + ((u >> 16) & 1u);          // RNE; inputs finite, non-NaN
    return (unsigned short)(u >> 16);
}
static __device__ __forceinline__ unsigned pack2(float a, float b) {
    return (unsigned)f2bf(a) | ((unsigned)f2bf(b) << 16);
}
// order LDS phases without cross-wave barriers (per-wave scratch only)
static __device__ __forceinline__ void lds_fence() {
    asm volatile("s_waitcnt lgkmcnt(0)" ::: "memory");
}

// ============ encode: 1 thread = (point, level); 1 level per block ============
// XCD swizzle: level l's blocks sit at blockIdx % 8 == l % 8, so XCD k (round-
// robin dispatch) touches only tables k and k+8 (<= ~4.2 MB -> per-XCD L2).
__global__ __launch_bounds__(256) void ngp_encode(
    const float* __restrict__ x, const float* __restrict__ tables,
    unsigned* __restrict__ feat, int N, int PB)
{
    const int g  = blockIdx.x;
    const int r  = g & 7;
    const int i  = g >> 3;            // [0, 2*PB)
    const int hi = (i >= PB);
    const int l  = r + (hi << 3);
    const int pb = i - (hi ? PB : 0);
    const int n  = pb * 256 + threadIdx.x;
    if (n >= N) return;

    const float2 xy = ((const float2*)x)[n];
    const float res = RES[l];
    const float sx = xy.x * res, sy = xy.y * res;
    const float fx = floorf(sx),  fy = floorf(sy);
    const float ux = sx - fx,     uy = sy - fy;
    const unsigned ix = (unsigned)(int)fx, iy = (unsigned)(int)fy;
    const unsigned hy0 = iy * PRIME, hy1 = (iy + 1u) * PRIME;
    const unsigned i00 = (ix ^ hy0) & TMASK;
    const unsigned i10 = ((ix + 1u) ^ hy0) & TMASK;
    const unsigned i01 = (ix ^ hy1) & TMASK;
    const unsigned i11 = ((ix + 1u) ^ hy1) & TMASK;
    const float2* tb = (const float2*)(tables + (size_t)l * (TSZ * 2));
    const float2 f00 = tb[i00], f10 = tb[i10], f01 = tb[i01], f11 = tb[i11];
    const float w00 = (1.f - ux) * (1.f - uy);
    const float w10 = ux * (1.f - uy);
    const float w01 = (1.f - ux) * uy;
    const float w11 = ux * uy;
    const float e0 = w00*f00.x + w10*f10.x + w01*f01.x + w11*f11.x;
    const float e1 = w00*f00.y + w10*f10.y + w01*f01.y + w11*f11.y;
    feat[(size_t)l * N + n] = pack2(e0, e1);       // coalesced
}

// ============ MLP via MFMA 16x16x32 bf16 ============
// Layouts (m89/m120-verified): A[m=lane&15][k=quad*8+j], B[k=quad*8+j][n=lane&15],
// C/D col=lane&15 row=quad*4+reg.
__global__ __launch_bounds__(256) void ngp_mlp(
    const unsigned* __restrict__ feat,
    const float* __restrict__ W0, const float* __restrict__ b0,
    const float* __restrict__ W1, const float* __restrict__ b1,
    const float* __restrict__ W2, const float* __restrict__ b2,
    float* __restrict__ out, int N)
{
    __shared__ uint4 sB0[4 * 64];    // W0 32x64 -> 4 col-tiles of B frags
    __shared__ uint4 sB1[8 * 64];    // W1 64x64 -> 2 k-tiles x 4 col-tiles
    __shared__ uint4 sB2[2 * 64];    // W2 64x16(pad) -> 2 k-tiles
    __shared__ __align__(16) unsigned short hscr[4][16][72];  // per-wave, pitch 72

    const int tid  = threadIdx.x;
    const int lane = tid & 63;
    const int w    = tid >> 6;
    const int c    = lane & 15;
    const int quad = lane >> 4;

    // ---- build B fragments in LDS (bf16, B-operand layout) ----
    {
        const int f = tid >> 6;      // 0..3
        Frag t0;
        #pragma unroll
        for (int j = 0; j < 8; ++j)
            t0.s[j] = f2bf(W0[(quad * 8 + j) * 64 + f * 16 + c]);
        sB0[f * 64 + lane] = t0.q;

        #pragma unroll
        for (int pass = 0; pass < 2; ++pass) {
            const int ff = f + pass * 4;        // 0..7
            const int kt = ff >> 2, tt = ff & 3;
            Frag t1;
            #pragma unroll
            for (int j = 0; j < 8; ++j)
                t1.s[j] = f2bf(W1[(kt * 32 + quad * 8 + j) * 64 + tt * 16 + c]);
            sB1[ff * 64 + lane] = t1.q;
        }
        if (f < 2) {
            Frag t2;
            #pragma unroll
            for (int j = 0; j < 8; ++j) {
                const float v = (c < 3) ? W2[(f * 32 + quad * 8 + j) * 3 + c] : 0.f;
                t2.s[j] = f2bf(v);
            }
            sB2[f * 64 + lane] = t2.q;
        }
    }
    __syncthreads();

    // ---- preload B frags + biases to registers ----
    Frag B0f[4], B1f[8], B2f[2];
    #pragma unroll
    for (int t = 0; t < 4; ++t) B0f[t].q = sB0[t * 64 + lane];
    #pragma unroll
    for (int f = 0; f < 8; ++f) B1f[f].q = sB1[f * 64 + lane];
    #pragma unroll
    for (int f = 0; f < 2; ++f) B2f[f].q = sB2[f * 64 + lane];

    float bias0[4], bias1[4];
    #pragma unroll
    for (int t = 0; t < 4; ++t) { bias0[t] = b0[t * 16 + c]; bias1[t] = b1[t * 16 + c]; }
    const float bias2 = (c < 3) ? b2[c] : 0.f;

    // ---- 4 tiles of 16 points per wave ----
    #pragma unroll 1
    for (int it = 0; it < 4; ++it) {
        const int n0 = blockIdx.x * 256 + w * 64 + it * 16;

        // A0 directly from feat: dword i = levels quad*4+i -> k = quad*8+2i,2i+1
        Frag a0;
        #pragma unroll
        for (int i = 0; i < 4; ++i)
            a0.u[i] = feat[(size_t)(quad * 4 + i) * N + n0 + c];

        f32x4 acc0[4];
        #pragma unroll
        for (int t = 0; t < 4; ++t) {
            f32x4 cin = {bias0[t], bias0[t], bias0[t], bias0[t]};
            acc0[t] = __builtin_amdgcn_mfma_f32_16x16x32_bf16(a0.v, B0f[t].v, cin, 0, 0, 0);
        }

        // h1 = relu(acc0) -> LDS scratch [point][neuron]
        lds_fence();
        #pragma unroll
        for (int t = 0; t < 4; ++t)
            #pragma unroll
            for (int rr = 0; rr < 4; ++rr)
                hscr[w][quad * 4 + rr][t * 16 + c] = f2bf(fmaxf(acc0[t][rr], 0.f));

        lds_fence();
        Frag a1[2];
        #pragma unroll
        for (int kt = 0; kt < 2; ++kt)
            a1[kt].q = *(const uint4*)&hscr[w][c][kt * 32 + quad * 8];

        f32x4 acc1[4];
        #pragma unroll
        for (int t = 0; t < 4; ++t) {
            f32x4 cin = {bias1[t], bias1[t], bias1[t], bias1[t]};
            cin = __builtin_amdgcn_mfma_f32_16x16x32_bf16(a1[0].v, B1f[t].v, cin, 0, 0, 0);
            acc1[t] = __builtin_amdgcn_mfma_f32_16x16x32_bf16(a1[1].v, B1f[4 + t].v, cin, 0, 0, 0);
        }

        // h2 = relu(acc1) -> LDS scratch
        lds_fence();
        #pragma unroll
        for (int t = 0; t < 4; ++t)
            #pragma unroll
            for (int rr = 0; rr < 4; ++rr)
                hscr[w][quad * 4 + rr][t * 16 + c] = f2bf(fmaxf(acc1[t][rr], 0.f));

        lds_fence();
        Frag a2[2];
        #pragma unroll
        for (int kt = 0; kt < 2; ++kt)
            a2[kt].q = *(const uint4*)&hscr[w][c][kt * 32 + quad * 8];

        f32x4 cin2 = {bias2, bias2, bias2, bias2};
        cin2 = __builtin_amdgcn_mfma_f32_16x16x32_bf16(a2[0].v, B2f[0].v, cin2, 0, 0, 0);
        f32x4 acc2 = __builtin_amdgcn_mfma_f32_16x16x32_bf16(a2[1].v, B2f[1].v, cin2, 0, 0, 0);

        // sigmoid + store: lane col c<3, rows quad*4+rr
        if (c < 3) {
            #pragma unroll
            for (int rr = 0; rr < 4; ++rr) {
                const float s = 1.f / (1.f + __expf(-acc2[rr]));
                out[(size_t)(n0 + quad * 4 + rr) * 3 + c] = s;
            }
        }
    }
}

extern "C" void kernel_launch(void* const* d_in, const int* in_sizes, int n_in,
                              void* d_out, int out_size, void* d_ws, size_t ws_size,
                              hipStream_t stream) {
    const float* x      = (const float*)d_in[0];
    const float* tables = (const float*)d_in[1];
    const float* W0     = (const float*)d_in[2];
    const float* b0     = (const float*)d_in[3];
    const float* W1     = (const float*)d_in[4];
    const float* b1     = (const float*)d_in[5];
    const float* W2     = (const float*)d_in[6];
    const float* b2     = (const float*)d_in[7];
    float* out = (float*)d_out;
    unsigned* feat = (unsigned*)d_ws;          // LVLS * N * 4 B = 64 MB

    const int N  = in_sizes[0] / 2;
    const int PB = (N + 255) / 256;
    ngp_encode<<<16 * PB, 256, 0, stream>>>(x, tables, feat, N, PB);
    ngp_mlp<<<PB, 256, 0, stream>>>(feat, W0, b0, W1, b1, W2, b2, out, N);
}